// Round 4
// baseline (152.851 us; speedup 1.0000x reference)
//
#include <hip/hip_runtime.h>
#include <math.h>

#define HW_ 6400
#define C_ 256
#define CP_ 19
#define CH_ 16   // channels per aggT block

typedef __bf16 bf16x8 __attribute__((ext_vector_type(8)));
typedef float  f32x4  __attribute__((ext_vector_type(4)));

// RNE float -> bf16 bits
static __device__ __forceinline__ unsigned short f2bf(float f) {
    union { float f; unsigned int u; } x; x.f = f;
    unsigned int r = x.u + 0x7FFF + ((x.u >> 16) & 1);
    return (unsigned short)(r >> 16);
}

// ---------------------------------------------------------------------------
// wgemm: W = W_fuse @ W_feat (256^3), BN folded.
//   block o, thread c:
//     WTb[o][c] = (sum_m wfuse[o][m]*wfeat[m][c]) * scale[c]   (bf16, A-operand)
//     wsum[o]   = sum_c W[o][c]*shift[c]                        (fp32)
// ---------------------------------------------------------------------------
__global__ __launch_bounds__(256) void wgemm_kernel(
    const float* __restrict__ wfeat, const float* __restrict__ wfuse,
    const float* __restrict__ g, const float* __restrict__ be,
    const float* __restrict__ mu, const float* __restrict__ var,
    unsigned short* __restrict__ WTb, float* __restrict__ wsum)
{
    const int o = blockIdx.x, c = threadIdx.x;
    __shared__ float row[C_];
    __shared__ float red[C_];
    row[c] = wfuse[o * C_ + c];
    __syncthreads();
    float acc = 0.0f;
#pragma unroll 8
    for (int m = 0; m < C_; ++m) acc += row[m] * wfeat[m * C_ + c];
    float scale = g[c] * rsqrtf(var[c] + 1e-5f);
    float shift = be[c] - mu[c] * scale;
    WTb[o * C_ + c] = f2bf(acc * scale);
    red[c] = acc * shift;
    __syncthreads();
    for (int s = 128; s > 0; s >>= 1) {
        if (c < s) red[c] += red[c + s];
        __syncthreads();
    }
    if (c == 0) wsum[o] = red[0];
}

// ---------------------------------------------------------------------------
// affinity: one wave per pixel, one lane per neighbor k (49 of 64 lanes).
//   Output k-major aff[49][HW] fp32 + S[p] = in-bounds weight sum.
// ---------------------------------------------------------------------------
__global__ __launch_bounds__(256) void affinity_kernel(
    const float* __restrict__ cp, const float* __restrict__ sigma,
    float* __restrict__ aff, float* __restrict__ S)
{
    const int lane = threadIdx.x & 63;
    const int p = blockIdx.x * 4 + (threadIdx.x >> 6);   // 1600 blocks -> 6400 px
    const int h = p / 80, w = p - h * 80;
    const int k = (lane < 49) ? lane : 48;
    const int i = k / 7, j = k - i * 7;
    const int hh = h + i - 3, ww = w + j - 3;
    const bool ok = (hh >= 0) & (hh < 80) & (ww >= 0) & (ww < 80);
    const float msk = ok ? 1.0f : 0.0f;                  // zero-pad semantics
    int q = hh * 80 + ww;
    q = min(max(q, 0), HW_ - 1);                         // always-legal address

    float s = fmaxf(sigma[0], 0.0f);
    float inv_denom = 1.0f / (2.0f * s * s + 1e-8f);

    float d = 0.0f;
#pragma unroll
    for (int c = 0; c < CP_; ++c) {
        float u = cp[c * HW_ + q];
        float ctr = __shfl(u, 24, 64);                   // lane 24 == center px
        float t = u * msk - ctr;
        d += t * t;
    }
    float raw = __expf(-d * inv_denom);
    float e = (lane < 49) ? __expf(raw) : 0.0f;          // softmax numerator
    float einb = (ok && lane < 49) ? e : 0.0f;
    float sum = e, sumi = einb;
#pragma unroll
    for (int off = 32; off; off >>= 1) {
        sum  += __shfl_xor(sum,  off, 64);
        sumi += __shfl_xor(sumi, off, 64);
    }
    if (lane < 49) aff[k * HW_ + p] = e / sum;
    if (lane == 0) S[p] = sumi / sum;
}

// ---------------------------------------------------------------------------
// aggT: aggT[p][c] (bf16) = sum_k aff[k][p] * x[c][neighbor(p,k)]  (zero-pad)
//   Block = 256 contiguous pixels x 16-channel chunk. aff held in 49 VGPRs
//   per thread (amortized over 16 channels); x rows staged in LDS per channel.
//   Output layout [p][c] = MFMA B-operand layout; 16B store per 8 channels.
// ---------------------------------------------------------------------------
__global__ __launch_bounds__(256) void aggT_kernel(
    const float* __restrict__ x, const float* __restrict__ aff,
    unsigned short* __restrict__ aggT)
{
    const int p = blockIdx.x * 256 + threadIdx.x;        // grid.x = 25
    const int h = p / 80, w = p - h * 80;
    const int c0 = blockIdx.y * CH_;                     // grid.y = 16

    float a[49];
#pragma unroll
    for (int k = 0; k < 49; ++k) a[k] = aff[k * HW_ + p];

    const int h0 = (blockIdx.x * 256) / 80;
    const int h1 = (blockIdx.x * 256 + 255) / 80;
    const int rlo = max(h0 - 3, 0);
    const int rhi = min(h1 + 3, 79);
    const int nel = (rhi - rlo + 1) * 80;                // <= 800

    __shared__ float xs[800];
    float obuf[8];

    for (int cc = 0; cc < CH_; ++cc) {
        const int c = c0 + cc;
        const float* xc = x + c * HW_ + rlo * 80;
        for (int t = threadIdx.x; t < nel; t += 256) xs[t] = xc[t];
        __syncthreads();
        float acc = 0.0f;
#pragma unroll
        for (int i = 0; i < 7; ++i) {
            int hh = h + i - 3;
            if (hh >= 0 && hh < 80) {
                int rbase = (hh - rlo) * 80 + w - 3;
#pragma unroll
                for (int j = 0; j < 7; ++j) {
                    int ww = w + j - 3;
                    float v = (ww >= 0 && ww < 80) ? xs[rbase + j] : 0.0f;
                    acc += a[i * 7 + j] * v;
                }
            }
        }
        obuf[cc & 7] = acc;
        if ((cc & 7) == 7) {
            unsigned int pk[4];
#pragma unroll
            for (int t = 0; t < 4; ++t)
                pk[t] = (unsigned int)f2bf(obuf[2 * t]) |
                        ((unsigned int)f2bf(obuf[2 * t + 1]) << 16);
            *(uint4*)&aggT[p * C_ + c0 + (cc & ~7)] =
                make_uint4(pk[0], pk[1], pk[2], pk[3]);
        }
        __syncthreads();
    }
}

// ---------------------------------------------------------------------------
// MFMA GEMM: out[m][p] = x[m][p] + wsum[m]*S[p] + sum_c A[m][c]*B[c][p]
//   A = WTb [256][256] bf16 row-major; B via aggT [p][c] bf16.
//   No LDS: both fragments are direct 16B global loads (8 consecutive c).
//   Block 256 thr = 4 waves; wave tile 64x64; grid (25, 4) -> 100 blocks.
// ---------------------------------------------------------------------------
__global__ __launch_bounds__(256) void mfma_gemm_kernel(
    const unsigned short* __restrict__ WTb, const unsigned short* __restrict__ aggT,
    const float* __restrict__ wsum, const float* __restrict__ S,
    const float* __restrict__ x, float* __restrict__ out)
{
    const int wave = threadIdx.x >> 6, lane = threadIdx.x & 63;
    const int q = lane >> 4, l15 = lane & 15;
    const int bm = blockIdx.y * 64;
    const int n0 = blockIdx.x * 256 + wave * 64;

    f32x4 acc[4][4];
#pragma unroll
    for (int mi = 0; mi < 4; ++mi)
#pragma unroll
        for (int ni = 0; ni < 4; ++ni) acc[mi][ni] = (f32x4){0.f, 0.f, 0.f, 0.f};

#pragma unroll
    for (int k0 = 0; k0 < 256; k0 += 32) {
        bf16x8 af[4], bf[4];
#pragma unroll
        for (int mi = 0; mi < 4; ++mi)
            af[mi] = *(const bf16x8*)&WTb[(bm + mi * 16 + l15) * C_ + k0 + q * 8];
#pragma unroll
        for (int ni = 0; ni < 4; ++ni)
            bf[ni] = *(const bf16x8*)&aggT[(n0 + ni * 16 + l15) * C_ + k0 + q * 8];
#pragma unroll
        for (int mi = 0; mi < 4; ++mi)
#pragma unroll
            for (int ni = 0; ni < 4; ++ni)
                acc[mi][ni] = __builtin_amdgcn_mfma_f32_16x16x32_bf16(
                    af[mi], bf[ni], acc[mi][ni], 0, 0, 0);
    }

#pragma unroll
    for (int mi = 0; mi < 4; ++mi) {
#pragma unroll
        for (int ni = 0; ni < 4; ++ni) {
            int p = n0 + ni * 16 + l15;
            float Sp = S[p];
#pragma unroll
            for (int r = 0; r < 4; ++r) {
                int m = bm + mi * 16 + q * 4 + r;
                out[m * HW_ + p] = x[m * HW_ + p] + wsum[m] * Sp + acc[mi][ni][r];
            }
        }
    }
}

// ---------------------------------------------------------------------------
extern "C" void kernel_launch(void* const* d_in, const int* in_sizes, int n_in,
                              void* d_out, int out_size, void* d_ws, size_t ws_size,
                              hipStream_t stream) {
    const float* x      = (const float*)d_in[0];  // (1,256,80,80)
    const float* cp     = (const float*)d_in[1];  // (1,19,80,80)
    const float* sigma  = (const float*)d_in[2];  // (1,)
    const float* w_feat = (const float*)d_in[3];  // (256,256)
    const float* w_fuse = (const float*)d_in[4];  // (256,256)
    const float* g      = (const float*)d_in[5];
    const float* be     = (const float*)d_in[6];
    const float* mu     = (const float*)d_in[7];
    const float* var    = (const float*)d_in[8];
    float* out = (float*)d_out;

    char* wsb = (char*)d_ws;
    unsigned short* WTb  = (unsigned short*)wsb;              // 256*256*2B = 128KB
    unsigned short* aggT = (unsigned short*)(wsb + 131072);   // 6400*256*2B = 3.2MB
    float* wsum = (float*)(wsb + 131072 + 3276800);           // 1KB
    float* S    = wsum + 256;                                 // 25.6KB
    float* aff  = S + HW_;                                    // 1.25MB
    // total ~4.7 MiB of ws

    wgemm_kernel<<<256, 256, 0, stream>>>(w_feat, w_fuse, g, be, mu, var, WTb, wsum);
    affinity_kernel<<<1600, 256, 0, stream>>>(cp, sigma, aff, S);
    aggT_kernel<<<dim3(25, 16), 256, 0, stream>>>(x, aff, aggT);
    // out = x + wsum*S + W' * aggx
    mfma_gemm_kernel<<<dim3(25, 4), 256, 0, stream>>>(WTb, aggT, wsum, S, x, out);
}

// Round 5
// 132.958 us; speedup vs baseline: 1.1496x; 1.1496x over previous
//
#include <hip/hip_runtime.h>
#include <math.h>

#define HW_ 6400
#define C_ 256
#define CP_ 19

typedef __bf16 bf16x8 __attribute__((ext_vector_type(8)));
typedef float  f32x4  __attribute__((ext_vector_type(4)));

// RNE float -> bf16 bits
static __device__ __forceinline__ unsigned short f2bf(float f) {
    union { float f; unsigned int u; } x; x.f = f;
    unsigned int r = x.u + 0x7FFF + ((x.u >> 16) & 1);
    return (unsigned short)(r >> 16);
}
static __device__ __forceinline__ float bf2f(unsigned short u) {
    union { unsigned int ui; float fv; } cv;
    cv.ui = ((unsigned int)u) << 16;
    return cv.fv;
}

// ---------------------------------------------------------------------------
// wgemm: W = W_fuse @ W_feat (256^3), BN folded.
//   WTb[o][c] = (sum_m wfuse[o][m]*wfeat[m][c]) * scale[c]   (bf16, A-operand)
//   wsum[o]   = sum_c W[o][c]*shift[c]                        (fp32)
// ---------------------------------------------------------------------------
__global__ __launch_bounds__(256) void wgemm_kernel(
    const float* __restrict__ wfeat, const float* __restrict__ wfuse,
    const float* __restrict__ g, const float* __restrict__ be,
    const float* __restrict__ mu, const float* __restrict__ var,
    unsigned short* __restrict__ WTb, float* __restrict__ wsum)
{
    const int o = blockIdx.x, c = threadIdx.x;
    __shared__ float row[C_];
    __shared__ float red[C_];
    row[c] = wfuse[o * C_ + c];
    __syncthreads();
    float acc = 0.0f;
#pragma unroll 8
    for (int m = 0; m < C_; ++m) acc += row[m] * wfeat[m * C_ + c];
    float scale = g[c] * rsqrtf(var[c] + 1e-5f);
    float shift = be[c] - mu[c] * scale;
    WTb[o * C_ + c] = f2bf(acc * scale);
    red[c] = acc * shift;
    __syncthreads();
    for (int s = 128; s > 0; s >>= 1) {
        if (c < s) red[c] += red[c + s];
        __syncthreads();
    }
    if (c == 0) wsum[o] = red[0];
}

// ---------------------------------------------------------------------------
// affinity: one wave per pixel, one lane per neighbor k (49 of 64 lanes).
//   Output k-major affb[49][HW] bf16 + S[p] = in-bounds weight sum (fp32).
// ---------------------------------------------------------------------------
__global__ __launch_bounds__(256) void affinity_kernel(
    const float* __restrict__ cp, const float* __restrict__ sigma,
    unsigned short* __restrict__ affb, float* __restrict__ S)
{
    const int lane = threadIdx.x & 63;
    const int p = blockIdx.x * 4 + (threadIdx.x >> 6);   // 1600 blocks -> 6400 px
    const int h = p / 80, w = p - h * 80;
    const int k = (lane < 49) ? lane : 48;
    const int i = k / 7, j = k - i * 7;
    const int hh = h + i - 3, ww = w + j - 3;
    const bool ok = (hh >= 0) & (hh < 80) & (ww >= 0) & (ww < 80);
    const float msk = ok ? 1.0f : 0.0f;                  // zero-pad semantics
    int q = hh * 80 + ww;
    q = min(max(q, 0), HW_ - 1);                         // always-legal address

    float s = fmaxf(sigma[0], 0.0f);
    float inv_denom = 1.0f / (2.0f * s * s + 1e-8f);

    float d = 0.0f;
#pragma unroll
    for (int c = 0; c < CP_; ++c) {
        float u = cp[c * HW_ + q];
        float ctr = __shfl(u, 24, 64);                   // lane 24 == center px
        float t = u * msk - ctr;
        d += t * t;
    }
    float raw = __expf(-d * inv_denom);
    float e = (lane < 49) ? __expf(raw) : 0.0f;          // softmax numerator
    float einb = (ok && lane < 49) ? e : 0.0f;
    float sum = e, sumi = einb;
#pragma unroll
    for (int off = 32; off; off >>= 1) {
        sum  += __shfl_xor(sum,  off, 64);
        sumi += __shfl_xor(sumi, off, 64);
    }
    if (lane < 49) affb[k * HW_ + p] = f2bf(e / sum);
    if (lane == 0) S[p] = sumi / sum;
}

// ---------------------------------------------------------------------------
// agg8: aggT[p][c] (bf16) = sum_k aff[k][p] * x[c][neighbor(p,k)] (zero-pad)
//   Thread = 8 consecutive px x 1 ch. Block = 32 px-groups x 8 channels
//   -> grid 800 blocks (3.1 waves/SIMD), no barriers in compute loop.
//   Per kernel row i: 4 clamped/masked float4 x loads + 7 bf16x8 aff loads
//   + 56 FMA. Epilogue: LDS transpose -> packed 16B [p][c] bf16 stores.
// ---------------------------------------------------------------------------
__global__ __launch_bounds__(256) void agg8_kernel(
    const float* __restrict__ x, const unsigned short* __restrict__ affb,
    unsigned short* __restrict__ aggT)
{
    const int b = blockIdx.x;            // 800 = 25 px-tiles * 32 ch-tiles
    const int pgt = b % 25, cht = b / 25;
    const int ch_l = threadIdx.x >> 5, pg_l = threadIdx.x & 31;
    const int pg = pgt * 32 + pg_l;      // px-group (8 px each)
    const int p0 = pg * 8;
    const int h = pg / 10, w0 = (pg - (pg / 10) * 10) * 8;
    const int c = cht * 8 + ch_l;
    const float* xc = x + c * HW_;

    float acc[8] = {0.f, 0.f, 0.f, 0.f, 0.f, 0.f, 0.f, 0.f};

#pragma unroll
    for (int i = 0; i < 7; ++i) {
        int hh = h + i - 3;
        if (hh < 0 || hh >= 80) continue;
        // x columns [w0-4, w0+12), clamped to row (garbage masked below)
        float f[16];
        const int rb = hh * 80;
#pragma unroll
        for (int t = 0; t < 4; ++t) {
            int lin = rb + w0 - 4 + 4 * t;
            lin = min(max(lin, rb), rb + 76);
            *(float4*)&f[4 * t] = *(const float4*)&xc[lin];
        }
#pragma unroll
        for (int e = 0; e < 16; ++e) {
            int col = w0 - 4 + e;
            f[e] = (col >= 0 && col < 80) ? f[e] : 0.0f;
        }
#pragma unroll
        for (int j = 0; j < 7; ++j) {
            const int k = i * 7 + j;
            unsigned short u8[8];
            *(uint4*)u8 = *(const uint4*)&affb[k * HW_ + p0];
#pragma unroll
            for (int px = 0; px < 8; ++px)
                acc[px] += bf2f(u8[px]) * f[px + j + 1];
        }
    }

    // LDS transpose: [256 px][8 ch] fp32, then packed bf16 stores
    __shared__ float so[256][9];
#pragma unroll
    for (int px = 0; px < 8; ++px) so[pg_l * 8 + px][ch_l] = acc[px];
    __syncthreads();
    const int t = threadIdx.x;           // px within tile
    unsigned int pk[4];
#pragma unroll
    for (int d = 0; d < 4; ++d) {
        unsigned int lo = f2bf(so[t][2 * d]);
        unsigned int hi = f2bf(so[t][2 * d + 1]);
        pk[d] = lo | (hi << 16);
    }
    const int p = pgt * 256 + t;
    *(uint4*)&aggT[p * C_ + cht * 8] = make_uint4(pk[0], pk[1], pk[2], pk[3]);
}

// ---------------------------------------------------------------------------
// MFMA GEMM: out[m][p] = x[m][p] + wsum[m]*S[p] + sum_c A[m][c]*B[c][p]
//   A = WTb [256][256] bf16 row-major; B via aggT [p][c] bf16.
//   No LDS: both fragments are direct 16B global loads (8 consecutive c).
//   Block 256 thr = 4 waves; wave tile 64x64; grid (25, 4) -> 100 blocks.
// ---------------------------------------------------------------------------
__global__ __launch_bounds__(256) void mfma_gemm_kernel(
    const unsigned short* __restrict__ WTb, const unsigned short* __restrict__ aggT,
    const float* __restrict__ wsum, const float* __restrict__ S,
    const float* __restrict__ x, float* __restrict__ out)
{
    const int wave = threadIdx.x >> 6, lane = threadIdx.x & 63;
    const int q = lane >> 4, l15 = lane & 15;
    const int bm = blockIdx.y * 64;
    const int n0 = blockIdx.x * 256 + wave * 64;

    f32x4 acc[4][4];
#pragma unroll
    for (int mi = 0; mi < 4; ++mi)
#pragma unroll
        for (int ni = 0; ni < 4; ++ni) acc[mi][ni] = (f32x4){0.f, 0.f, 0.f, 0.f};

#pragma unroll
    for (int k0 = 0; k0 < 256; k0 += 32) {
        bf16x8 af[4], bf[4];
#pragma unroll
        for (int mi = 0; mi < 4; ++mi)
            af[mi] = *(const bf16x8*)&WTb[(bm + mi * 16 + l15) * C_ + k0 + q * 8];
#pragma unroll
        for (int ni = 0; ni < 4; ++ni)
            bf[ni] = *(const bf16x8*)&aggT[(n0 + ni * 16 + l15) * C_ + k0 + q * 8];
#pragma unroll
        for (int mi = 0; mi < 4; ++mi)
#pragma unroll
            for (int ni = 0; ni < 4; ++ni)
                acc[mi][ni] = __builtin_amdgcn_mfma_f32_16x16x32_bf16(
                    af[mi], bf[ni], acc[mi][ni], 0, 0, 0);
    }

#pragma unroll
    for (int mi = 0; mi < 4; ++mi) {
#pragma unroll
        for (int ni = 0; ni < 4; ++ni) {
            int p = n0 + ni * 16 + l15;
            float Sp = S[p];
#pragma unroll
            for (int r = 0; r < 4; ++r) {
                int m = bm + mi * 16 + q * 4 + r;
                out[m * HW_ + p] = x[m * HW_ + p] + wsum[m] * Sp + acc[mi][ni][r];
            }
        }
    }
}

// ---------------------------------------------------------------------------
extern "C" void kernel_launch(void* const* d_in, const int* in_sizes, int n_in,
                              void* d_out, int out_size, void* d_ws, size_t ws_size,
                              hipStream_t stream) {
    const float* x      = (const float*)d_in[0];  // (1,256,80,80)
    const float* cp     = (const float*)d_in[1];  // (1,19,80,80)
    const float* sigma  = (const float*)d_in[2];  // (1,)
    const float* w_feat = (const float*)d_in[3];  // (256,256)
    const float* w_fuse = (const float*)d_in[4];  // (256,256)
    const float* g      = (const float*)d_in[5];
    const float* be     = (const float*)d_in[6];
    const float* mu     = (const float*)d_in[7];
    const float* var    = (const float*)d_in[8];
    float* out = (float*)d_out;

    char* wsb = (char*)d_ws;
    unsigned short* WTb  = (unsigned short*)wsb;              // 128 KB
    unsigned short* aggT = (unsigned short*)(wsb + 131072);   // 3.2 MB
    float* wsum = (float*)(wsb + 131072 + 3276800);           // 1 KB
    float* S    = wsum + 256;                                 // 25.6 KB
    unsigned short* affb = (unsigned short*)(S + HW_);        // 627 KB
    // total ~4 MiB of ws

    wgemm_kernel<<<256, 256, 0, stream>>>(w_feat, w_fuse, g, be, mu, var, WTb, wsum);
    affinity_kernel<<<1600, 256, 0, stream>>>(cp, sigma, affb, S);
    agg8_kernel<<<800, 256, 0, stream>>>(x, affb, aggT);
    // out = x + wsum*S + W' * aggT^T
    mfma_gemm_kernel<<<dim3(25, 4), 256, 0, stream>>>(WTb, aggT, wsum, S, x, out);
}